// Round 9
// baseline (158.989 us; speedup 1.0000x reference)
//
#include <hip/hip_runtime.h>
#include <math.h>

#define HD 128
#define NPB 16
#define RPT 8

typedef __attribute__((ext_vector_type(8))) short bf16x8;
typedef __attribute__((ext_vector_type(4))) float f32x4;

__device__ inline short f2bf(float x) {   // RTNE f32->bf16
    union { float f; unsigned u; } v; v.f = x;
    unsigned r = v.u + 0x7fff + ((v.u >> 16) & 1);
    return (short)(r >> 16);
}
__device__ inline float bf2f(short x) {
    union { unsigned u; float f; } v;
    v.u = ((unsigned)(unsigned short)x) << 16;
    return v.f;
}

#define LOG2E 1.4426950408889634f
#define LN2   0.6931471805599453f

__device__ inline float fast_sigmoid(float x) {
    return __builtin_amdgcn_rcpf(1.0f + __builtin_amdgcn_exp2f(-LOG2E * x));
}
__device__ inline float fast_softplus(float x) {
    float t = __builtin_amdgcn_exp2f(-LOG2E * fabsf(x));
    return fmaxf(x, 0.0f) + LN2 * __builtin_amdgcn_logf(1.0f + t);
}

__device__ inline void accum8(float* a, const uint4 u) {  // += 8 bf16 packed in uint4
    a[0] += __uint_as_float(u.x << 16);
    a[1] += __uint_as_float(u.x & 0xffff0000u);
    a[2] += __uint_as_float(u.y << 16);
    a[3] += __uint_as_float(u.y & 0xffff0000u);
    a[4] += __uint_as_float(u.z << 16);
    a[5] += __uint_as_float(u.z & 0xffff0000u);
    a[6] += __uint_as_float(u.w << 16);
    a[7] += __uint_as_float(u.w & 0xffff0000u);
}

// ---- WtG build + degree histogram ----
// WtG[j][k] = bf16(Wcat[k][j]), j in 0..255 (j<128: W1 col j; j>=128: W2 col j-128), k in 0..127

__global__ __launch_bounds__(256) void wtg_hist(
    const float* __restrict__ W, short* __restrict__ WtG,
    const int* __restrict__ dst, int* __restrict__ deg, int n_edges)
{
    const int tid = blockIdx.x * 256 + threadIdx.x;
    const int total = gridDim.x * 256;
    for (int i = tid; i < 256 * 128; i += total) {
        int j = i >> 7, k = i & 127;
        float w = (j < HD) ? W[k * HD + j] : W[(HD + k) * HD + (j - HD)];
        WtG[i] = f2bf(w);
    }
    for (int e = tid; e < n_edges; e += total)
        atomicAdd(&deg[dst[e]], 1);
}

// ---- dense prep GEMM: m1b = bf16(h@W1), m2 = h@W2 + b ----
// Block: 32 rows, 4 waves. wave: 16 rows x 128 cols (half = which output matrix).
// A/B both use k = kf*32 + g*8 + slot (consistent bijection -> exact).
// C/D: col = lane&15, row = (lane>>4)*4 + reg  [HW-verified m89/m91].

__global__ __launch_bounds__(256) void prep_gemm(
    const float* __restrict__ h,     // [N][128] f32
    const short* __restrict__ WtG,   // [256][128] bf16
    const float* __restrict__ bias,  // [128] f32
    short* __restrict__ m1b,         // [N][128] bf16 out
    float* __restrict__ m2,          // [N][128] f32 out (h@W2 + b)
    int n_nodes)
{
    const int lane = threadIdx.x & 63;
    const int wv = threadIdx.x >> 6;           // 0..3
    const int m0 = blockIdx.x * 32 + (wv >> 1) * 16;
    const int half = wv & 1;                   // 0: m1, 1: m2
    if (m0 >= n_nodes) return;
    const int row = lane & 15;
    const int g = lane >> 4;

    int mA = m0 + row;
    if (mA > n_nodes - 1) mA = n_nodes - 1;

    bf16x8 a[4];
    #pragma unroll
    for (int kf = 0; kf < 4; ++kf) {
        const float4* p = (const float4*)(h + (size_t)mA * HD + kf * 32 + g * 8);
        float4 x = p[0], y = p[1];
        bf16x8 t = { f2bf(x.x), f2bf(x.y), f2bf(x.z), f2bf(x.w),
                     f2bf(y.x), f2bf(y.y), f2bf(y.z), f2bf(y.w) };
        a[kf] = t;
    }

    f32x4 acc[8];
    #pragma unroll
    for (int jt = 0; jt < 8; ++jt) acc[jt] = (f32x4){0.f, 0.f, 0.f, 0.f};

    #pragma unroll
    for (int jt = 0; jt < 8; ++jt) {
        const short* wj = WtG + (size_t)(half * HD + jt * 16 + row) * HD + g * 8;
        #pragma unroll
        for (int kf = 0; kf < 4; ++kf) {
            bf16x8 bf = *(const bf16x8*)(wj + kf * 32);
            acc[jt] = __builtin_amdgcn_mfma_f32_16x16x32_bf16(a[kf], bf, acc[jt], 0, 0, 0);
        }
    }

    const int nBase = m0 + g * 4;
    if (half == 0) {
        #pragma unroll
        for (int jt = 0; jt < 8; ++jt) {
            const int col = jt * 16 + row;
            #pragma unroll
            for (int r = 0; r < 4; ++r) {
                int n = nBase + r;
                if (n < n_nodes) m1b[(size_t)n * HD + col] = f2bf(acc[jt][r]);
            }
        }
    } else {
        #pragma unroll
        for (int jt = 0; jt < 8; ++jt) {
            const int col = jt * 16 + row;
            const float bc = bias[col];
            #pragma unroll
            for (int r = 0; r < 4; ++r) {
                int n = nBase + r;
                if (n < n_nodes) m2[(size_t)n * HD + col] = acc[jt][r] + bc;
            }
        }
    }
}

// ---------------- hierarchical scan ----------------

__global__ __launch_bounds__(1024) void scan_blocks(
    const int* __restrict__ deg, int* __restrict__ off,
    int* __restrict__ bsum, int n_nodes)
{
    __shared__ int wtot[16];
    const int t = threadIdx.x;
    const int lane = t & 63;
    const int wid = t >> 6;
    int idx = blockIdx.x * 1024 + t;
    int v = (idx < n_nodes) ? deg[idx] : 0;
    int incl = v;
    #pragma unroll
    for (int o = 1; o < 64; o <<= 1) {
        int y = __shfl_up(incl, o, 64);
        if (lane >= o) incl += y;
    }
    if (lane == 63) wtot[wid] = incl;
    __syncthreads();
    if (wid == 0) {
        int w = (lane < 16) ? wtot[lane] : 0;
        int wi = w;
        #pragma unroll
        for (int o = 1; o < 16; o <<= 1) {
            int y = __shfl_up(wi, o, 64);
            if (lane >= o) wi += y;
        }
        if (lane < 16) wtot[lane] = wi - w;
    }
    __syncthreads();
    int excl = wtot[wid] + incl - v;
    if (idx < n_nodes) off[idx] = excl;
    if (t == 1023) bsum[blockIdx.x] = wtot[15] + incl;
}

__global__ __launch_bounds__(64) void scan_partials(int* __restrict__ bsum, int nb)
{
    const int lane = threadIdx.x;
    int carry = 0;
    for (int base = 0; base < nb; base += 64) {
        int i = base + lane;
        int v = (i < nb) ? bsum[i] : 0;
        int incl = v;
        #pragma unroll
        for (int o = 1; o < 64; o <<= 1) {
            int y = __shfl_up(incl, o, 64);
            if (lane >= o) incl += y;
        }
        if (i < nb) bsum[i] = carry + incl - v;
        carry += __shfl(incl, 63, 64);
    }
}

__global__ __launch_bounds__(1024) void scan_apply(
    int* __restrict__ off, int* __restrict__ cur,
    const int* __restrict__ bsum, int n_nodes, int n_edges)
{
    int idx = blockIdx.x * 1024 + threadIdx.x;
    if (idx < n_nodes) {
        int v = off[idx] + bsum[blockIdx.x];
        off[idx] = v;
        cur[idx] = v;
    }
    if (idx == 0) off[n_nodes] = n_edges;
}

__global__ __launch_bounds__(256) void edge_fill(
    const int* __restrict__ src, const int* __restrict__ dst,
    int* __restrict__ cur, int* __restrict__ elist, int n_edges)
{
    int e = blockIdx.x * 256 + threadIdx.x;
    if (e < n_edges) {
        int d = dst[e];
        int pos = atomicAdd(&cur[d], 1);
        elist[pos] = src[e];
    }
}

// ---- gather + full epilogue: out[n] = sigmoid(sum_e m1b[src] + deg*m2[n]) + softplus(h[n]) ----
// 16 lanes/node, each lane owns 8 cols; f32 accumulate; sequential epilogue reads.

__global__ __launch_bounds__(256) void gather_ep(
    const short* __restrict__ m1b, const int* __restrict__ off,
    const int* __restrict__ elist, const float* __restrict__ m2,
    const float* __restrict__ h, float* __restrict__ out, int n_nodes)
{
    int g = (blockIdx.x * 256 + threadIdx.x) >> 4;   // node
    int lane = threadIdx.x & 15;
    if (g >= n_nodes) return;
    int beg = off[g], end = off[g + 1];
    const size_t lo = (size_t)(lane * 8);

    float a0[8], a1[8];
    #pragma unroll
    for (int q = 0; q < 8; ++q) { a0[q] = 0.f; a1[q] = 0.f; }

    int i = beg;
    for (; i + 4 <= end; i += 4) {
        int s0 = elist[i], s1 = elist[i + 1], s2 = elist[i + 2], s3 = elist[i + 3];
        uint4 v0 = *(const uint4*)(m1b + (size_t)s0 * HD + lo);
        uint4 v1 = *(const uint4*)(m1b + (size_t)s1 * HD + lo);
        uint4 v2 = *(const uint4*)(m1b + (size_t)s2 * HD + lo);
        uint4 v3 = *(const uint4*)(m1b + (size_t)s3 * HD + lo);
        accum8(a0, v0); accum8(a1, v1);
        accum8(a0, v2); accum8(a1, v3);
    }
    for (; i < end; ++i) {
        int s0 = elist[i];
        uint4 v0 = *(const uint4*)(m1b + (size_t)s0 * HD + lo);
        accum8(a0, v0);
    }

    const float dg = (float)(end - beg);
    const float4* pm = (const float4*)(m2 + (size_t)g * HD + lo);
    const float4* ph = (const float4*)(h + (size_t)g * HD + lo);
    float4 ma = pm[0], mb = pm[1], ha = ph[0], hb4 = ph[1];

    float mr[8] = { ma.x, ma.y, ma.z, ma.w, mb.x, mb.y, mb.z, mb.w };
    float hr[8] = { ha.x, ha.y, ha.z, ha.w, hb4.x, hb4.y, hb4.z, hb4.w };

    float o[8];
    #pragma unroll
    for (int q = 0; q < 8; ++q) {
        float agg = (a0[q] + a1[q]) + dg * mr[q];
        o[q] = fast_sigmoid(agg) + fast_softplus(hr[q]);
    }
    float4* po = (float4*)(out + (size_t)g * HD + lo);
    po[0] = (float4){o[0], o[1], o[2], o[3]};
    po[1] = (float4){o[4], o[5], o[6], o[7]};
}

// ================== fallback tiers ==================

__global__ __launch_bounds__(256) void wt_convert(
    const float* __restrict__ W, short* __restrict__ Wt)
{
    int idx = blockIdx.x * 256 + threadIdx.x;
    int j = idx >> 8;
    int k = idx & 255;
    Wt[idx] = f2bf(W[k * HD + j]);
}

__global__ __launch_bounds__(256) void mpnn_scatter(
    const float* __restrict__ h, const int* __restrict__ src,
    const int* __restrict__ dst, float* __restrict__ S,
    int* __restrict__ deg, int n_edges)
{
    int gid = blockIdx.x * 256 + threadIdx.x;
    int e = gid >> 5;
    if (e >= n_edges) return;
    int lane = gid & 31;
    int s = src[e], d = dst[e];
    float4 v = *(const float4*)(h + (size_t)s * HD + lane * 4);
    float* srow = S + (size_t)d * HD + lane * 4;
    atomicAdd(srow + 0, v.x);
    atomicAdd(srow + 1, v.y);
    atomicAdd(srow + 2, v.z);
    atomicAdd(srow + 3, v.w);
    if (lane == 0) atomicAdd(deg + d, 1);
}

__global__ __launch_bounds__(256) void mpnn_node_mfma(
    const float* __restrict__ h,
    const short* __restrict__ Wt,    // [128][256]
    const float* __restrict__ bias,
    const int* __restrict__ deg,
    float* __restrict__ S,
    int n_nodes)
{
    const int lane = threadIdx.x & 63;
    const int wv = threadIdx.x >> 6;
    const int m0 = blockIdx.x * 32 + (wv >> 1) * 16;
    const int c0 = (wv & 1) * 64;
    if (m0 >= n_nodes) return;
    const int row = lane & 15;
    const int g = lane >> 4;

    const int nBase = m0 + g * 4;
    float dgO[4], hv[4][4], bc[4];
    #pragma unroll
    for (int r = 0; r < 4; ++r) {
        int n = nBase + r;
        int nc = (n < n_nodes) ? n : (n_nodes - 1);
        dgO[r] = (float)deg[nc];
        #pragma unroll
        for (int jt = 0; jt < 4; ++jt)
            hv[jt][r] = h[(size_t)nc * HD + c0 + jt * 16 + row];
    }
    #pragma unroll
    for (int jt = 0; jt < 4; ++jt) bc[jt] = bias[c0 + jt * 16 + row];

    int mA = m0 + row;
    if (mA > n_nodes - 1) mA = n_nodes - 1;
    const float dgA = (float)deg[mA];

    bf16x8 a[8];
    #pragma unroll
    for (int kf = 0; kf < 4; ++kf) {
        const float4* p = (const float4*)(S + (size_t)mA * HD + kf * 32 + g * 8);
        float4 x = p[0], y = p[1];
        bf16x8 t = { f2bf(x.x), f2bf(x.y), f2bf(x.z), f2bf(x.w),
                     f2bf(y.x), f2bf(y.y), f2bf(y.z), f2bf(y.w) };
        a[kf] = t;
    }
    #pragma unroll
    for (int kf = 0; kf < 4; ++kf) {
        const float4* p = (const float4*)(h + (size_t)mA * HD + kf * 32 + g * 8);
        float4 x = p[0], y = p[1];
        bf16x8 t = { f2bf(dgA * x.x), f2bf(dgA * x.y), f2bf(dgA * x.z), f2bf(dgA * x.w),
                     f2bf(dgA * y.x), f2bf(dgA * y.y), f2bf(dgA * y.z), f2bf(dgA * y.w) };
        a[4 + kf] = t;
    }

    f32x4 acc[4];
    #pragma unroll
    for (int jt = 0; jt < 4; ++jt) acc[jt] = (f32x4){0.f, 0.f, 0.f, 0.f};

    #pragma unroll
    for (int jt = 0; jt < 4; ++jt) {
        const short* wj = Wt + (size_t)(c0 + jt * 16 + row) * 256 + g * 8;
        #pragma unroll
        for (int kf = 0; kf < 8; ++kf) {
            bf16x8 bf = *(const bf16x8*)(wj + kf * 32);
            acc[jt] = __builtin_amdgcn_mfma_f32_16x16x32_bf16(a[kf], bf, acc[jt], 0, 0, 0);
        }
    }

    #pragma unroll
    for (int jt = 0; jt < 4; ++jt) {
        const int col = c0 + jt * 16 + row;
        #pragma unroll
        for (int r = 0; r < 4; ++r) {
            int n = nBase + r;
            if (n < n_nodes) {
                float agg = acc[jt][r] + dgO[r] * bc[jt];
                S[(size_t)n * HD + col] = fast_sigmoid(agg) + fast_softplus(hv[jt][r]);
            }
        }
    }
}

__global__ __launch_bounds__(256) void mpnn_node_f32(
    const float* __restrict__ h, const float* __restrict__ W,
    const float* __restrict__ b, const int* __restrict__ deg,
    float* __restrict__ S, int n_nodes)
{
    const int j = threadIdx.x & (HD - 1);
    const int g = threadIdx.x >> 7;
    const int n0 = blockIdx.x * NPB + g * RPT;

    float accS[RPT], accH[RPT];
    #pragma unroll
    for (int r = 0; r < RPT; ++r) { accS[r] = 0.f; accH[r] = 0.f; }

    int rmax = n_nodes - n0;
    if (rmax > RPT) rmax = RPT;
    if (rmax < 0) rmax = 0;

    for (int k = 0; k < HD; k += 4) {
        float w0 = W[(k + 0) * HD + j], w1 = W[(k + 1) * HD + j];
        float w2 = W[(k + 2) * HD + j], w3 = W[(k + 3) * HD + j];
        #pragma unroll
        for (int r = 0; r < RPT; ++r) if (r < rmax) {
            float4 a = *(const float4*)(S + (size_t)(n0 + r) * HD + k);
            accS[r] = fmaf(a.x, w0, fmaf(a.y, w1, fmaf(a.z, w2, fmaf(a.w, w3, accS[r]))));
        }
    }
    for (int k = 0; k < HD; k += 4) {
        float w0 = W[(HD + k + 0) * HD + j], w1 = W[(HD + k + 1) * HD + j];
        float w2 = W[(HD + k + 2) * HD + j], w3 = W[(HD + k + 3) * HD + j];
        #pragma unroll
        for (int r = 0; r < RPT; ++r) if (r < rmax) {
            float4 a = *(const float4*)(h + (size_t)(n0 + r) * HD + k);
            accH[r] = fmaf(a.x, w0, fmaf(a.y, w1, fmaf(a.z, w2, fmaf(a.w, w3, accH[r]))));
        }
    }
    __syncthreads();
    #pragma unroll
    for (int r = 0; r < RPT; ++r) if (r < rmax) {
        int n = n0 + r;
        float dg = (float)deg[n];
        float agg = accS[r] + dg * (accH[r] + b[j]);
        float hvv = h[(size_t)n * HD + j];
        S[(size_t)n * HD + j] = fast_sigmoid(agg) + fast_softplus(hvv);
    }
}

extern "C" void kernel_launch(void* const* d_in, const int* in_sizes, int n_in,
                              void* d_out, int out_size, void* d_ws, size_t ws_size,
                              hipStream_t stream)
{
    const float* h   = (const float*)d_in[0];
    const int*   src = (const int*)d_in[1];
    const int*   dst = (const int*)d_in[2];
    const float* W   = (const float*)d_in[3];
    const float* b   = (const float*)d_in[4];
    float* S = (float*)d_out;

    const int n_nodes = in_sizes[0] / HD;
    const int n_edges = in_sizes[1];
    const int WT_INTS = 2 * HD * HD / 2;
    const int nb = (n_nodes + 1023) / 1024;

    // ---- 16B-aligned ws layout for the transformed-gather path ----
    char* p = (char*)d_ws;
    auto align16 = [](char* q) { return (char*)(((uintptr_t)q + 15) & ~(uintptr_t)15); };
    p = align16(p); int* deg = (int*)p;     p += (size_t)n_nodes * 4;
    p = align16(p); int* off = (int*)p;     p += ((size_t)n_nodes + 1) * 4;
    p = align16(p); int* cur = (int*)p;     p += (size_t)n_nodes * 4;
    p = align16(p); int* elist = (int*)p;   p += (size_t)n_edges * 4;
    p = align16(p); short* WtG = (short*)p; p += (size_t)256 * HD * 2;
    p = align16(p); int* bsum = (int*)p;    p += (size_t)nb * 4;
    p = align16(p); short* m1b = (short*)p; p += (size_t)n_nodes * HD * 2;
    p = align16(p); float* m2 = (float*)p;  p += (size_t)n_nodes * HD * 4;
    const size_t need_top = (size_t)(p - (char*)d_ws);

    const size_t need_mid = ((size_t)n_nodes + WT_INTS + 8) * sizeof(int);

    if (ws_size >= need_top) {
        hipMemsetAsync(deg, 0, (size_t)n_nodes * sizeof(int), stream);
        wtg_hist<<<1024, 256, 0, stream>>>(W, WtG, dst, deg, n_edges);

        const int pblocks = (n_nodes + 31) / 32;
        prep_gemm<<<pblocks, 256, 0, stream>>>(h, WtG, b, m1b, m2, n_nodes);

        scan_blocks<<<nb, 1024, 0, stream>>>(deg, off, bsum, n_nodes);
        scan_partials<<<1, 64, 0, stream>>>(bsum, nb);
        scan_apply<<<nb, 1024, 0, stream>>>(off, cur, bsum, n_nodes, n_edges);

        edge_fill<<<(n_edges + 255) / 256, 256, 0, stream>>>(src, dst, cur, elist, n_edges);

        const int gblocks = (int)(((long long)n_nodes * 16 + 255) / 256);
        gather_ep<<<gblocks, 256, 0, stream>>>(m1b, off, elist, m2, h, S, n_nodes);
    } else if (ws_size >= need_mid) {
        // atomic scatter + MFMA node kernel
        int* deg2  = (int*)d_ws;
        short* Wt2 = (short*)(deg2 + n_nodes);
        hipMemsetAsync(d_out, 0, (size_t)n_nodes * HD * sizeof(float), stream);
        hipMemsetAsync(deg2, 0, (size_t)n_nodes * sizeof(int), stream);
        wt_convert<<<(2 * HD * HD) / 256, 256, 0, stream>>>(W, Wt2);
        const int sblocks = (int)(((long long)n_edges * 32 + 255) / 256);
        mpnn_scatter<<<sblocks, 256, 0, stream>>>(h, src, dst, S, deg2, n_edges);
        const int mblocks = (n_nodes + 31) / 32;
        mpnn_node_mfma<<<mblocks, 256, 0, stream>>>(h, Wt2, b, deg2, S, n_nodes);
    } else {
        int* deg2 = (int*)d_ws;
        hipMemsetAsync(d_out, 0, (size_t)n_nodes * HD * sizeof(float), stream);
        hipMemsetAsync(deg2, 0, (size_t)n_nodes * sizeof(int), stream);
        const int sblocks = (int)(((long long)n_edges * 32 + 255) / 256);
        mpnn_scatter<<<sblocks, 256, 0, stream>>>(h, src, dst, S, deg2, n_edges);
        const int nblocks = (n_nodes + NPB - 1) / NPB;
        mpnn_node_f32<<<nblocks, 256, 0, stream>>>(h, W, b, deg2, S, n_nodes);
    }
}

// Round 10
// 153.403 us; speedup vs baseline: 1.0364x; 1.0364x over previous
//
#include <hip/hip_runtime.h>
#include <math.h>

#define HD 128
#define NPB 16
#define RPT 8

typedef __attribute__((ext_vector_type(8))) short bf16x8;
typedef __attribute__((ext_vector_type(4))) float f32x4;

__device__ inline short f2bf(float x) {   // RTNE f32->bf16
    union { float f; unsigned u; } v; v.f = x;
    unsigned r = v.u + 0x7fff + ((v.u >> 16) & 1);
    return (short)(r >> 16);
}
__device__ inline float bf2f(short x) {
    union { unsigned u; float f; } v;
    v.u = ((unsigned)(unsigned short)x) << 16;
    return v.f;
}

#define LOG2E 1.4426950408889634f
#define LN2   0.6931471805599453f

__device__ inline float fast_sigmoid(float x) {
    return __builtin_amdgcn_rcpf(1.0f + __builtin_amdgcn_exp2f(-LOG2E * x));
}
__device__ inline float fast_softplus(float x) {
    float t = __builtin_amdgcn_exp2f(-LOG2E * fabsf(x));
    return fmaxf(x, 0.0f) + LN2 * __builtin_amdgcn_logf(1.0f + t);
}

__device__ inline void accum8(float* a, const uint4 u) {  // += 8 bf16 packed in uint4
    a[0] += __uint_as_float(u.x << 16);
    a[1] += __uint_as_float(u.x & 0xffff0000u);
    a[2] += __uint_as_float(u.y << 16);
    a[3] += __uint_as_float(u.y & 0xffff0000u);
    a[4] += __uint_as_float(u.z << 16);
    a[5] += __uint_as_float(u.z & 0xffff0000u);
    a[6] += __uint_as_float(u.w << 16);
    a[7] += __uint_as_float(u.w & 0xffff0000u);
}

// ---- WtG build + degree histogram ----
// WtG[j][k] = bf16(Wcat[k][j]), j in 0..255 (j<128: W1 col j; j>=128: W2 col j-128), k in 0..127

__global__ __launch_bounds__(256) void wtg_hist(
    const float* __restrict__ W, short* __restrict__ WtG,
    const int* __restrict__ dst, int* __restrict__ deg, int n_edges)
{
    const int tid = blockIdx.x * 256 + threadIdx.x;
    const int total = gridDim.x * 256;
    for (int i = tid; i < 256 * 128; i += total) {
        int j = i >> 7, k = i & 127;
        float w = (j < HD) ? W[k * HD + j] : W[(HD + k) * HD + (j - HD)];
        WtG[i] = f2bf(w);
    }
    for (int e = tid; e < n_edges; e += total)
        atomicAdd(&deg[dst[e]], 1);
}

// ---- dense prep GEMM: m1b = bf16(h@W1), m2 = h@W2 + b ----
// Block: 32 rows, 4 waves; wave = 16 rows x one half (128 cols), 32 MFMAs.
// C-tile staged in wave-private LDS, then read back row-contiguous for
// fully-coalesced 16B global stores (fixes R9's scattered 2/4B store epilogue).
// A/B both use k = kf*32 + g*8 + slot (consistent bijection -> exact).
// C/D: col = lane&15, row = (lane>>4)*4 + reg  [HW-verified m89/m91].

__global__ __launch_bounds__(256) void prep_gemm(
    const float* __restrict__ h,     // [N][128] f32
    const short* __restrict__ WtG,   // [256][128] bf16
    const float* __restrict__ bias,  // [128] f32
    short* __restrict__ m1b,         // [N][128] bf16 out
    float* __restrict__ m2,          // [N][128] f32 out (h@W2 + b)
    int n_nodes)
{
    __shared__ short sb[2][16][128];   // half=0 staging (waves 0,2) : 8 KB
    __shared__ float sf[2][16][128];   // half=1 staging (waves 1,3) : 16 KB

    const int lane = threadIdx.x & 63;
    const int wv = threadIdx.x >> 6;           // 0..3
    const int m0 = blockIdx.x * 32 + (wv >> 1) * 16;
    const int half = wv & 1;                   // 0: m1, 1: m2
    const int widx = wv >> 1;
    if (m0 >= n_nodes) return;
    const int row = lane & 15;
    const int g = lane >> 4;

    int mA = m0 + row;
    if (mA > n_nodes - 1) mA = n_nodes - 1;

    bf16x8 a[4];
    #pragma unroll
    for (int kf = 0; kf < 4; ++kf) {
        const float4* p = (const float4*)(h + (size_t)mA * HD + kf * 32 + g * 8);
        float4 x = p[0], y = p[1];
        bf16x8 t = { f2bf(x.x), f2bf(x.y), f2bf(x.z), f2bf(x.w),
                     f2bf(y.x), f2bf(y.y), f2bf(y.z), f2bf(y.w) };
        a[kf] = t;
    }

    f32x4 acc[8];
    #pragma unroll
    for (int jt = 0; jt < 8; ++jt) acc[jt] = (f32x4){0.f, 0.f, 0.f, 0.f};

    #pragma unroll
    for (int jt = 0; jt < 8; ++jt) {
        const short* wj = WtG + (size_t)(half * HD + jt * 16 + row) * HD + g * 8;
        #pragma unroll
        for (int kf = 0; kf < 4; ++kf) {
            bf16x8 bf = *(const bf16x8*)(wj + kf * 32);
            acc[jt] = __builtin_amdgcn_mfma_f32_16x16x32_bf16(a[kf], bf, acc[jt], 0, 0, 0);
        }
    }

    // ---- stage C-tile in LDS (scattered, cheap), then coalesced global stores ----
    if (half == 0) {
        #pragma unroll
        for (int jt = 0; jt < 8; ++jt)
            #pragma unroll
            for (int r = 0; r < 4; ++r)
                sb[widx][g * 4 + r][jt * 16 + row] = f2bf(acc[jt][r]);
        __builtin_amdgcn_s_waitcnt(0);   // lgkmcnt(0): wave-private region, no barrier
        #pragma unroll
        for (int it = 0; it < 4; ++it) {
            int rr = it * 4 + (lane >> 4);       // 0..15
            int c8 = lane & 15;                  // 16B chunk id
            int n = m0 + rr;
            bf16x8 v = *(const bf16x8*)&sb[widx][rr][c8 * 8];
            if (n < n_nodes)
                *(bf16x8*)(m1b + (size_t)n * HD + c8 * 8) = v;
        }
    } else {
        #pragma unroll
        for (int jt = 0; jt < 8; ++jt) {
            const float bc = bias[jt * 16 + row];
            #pragma unroll
            for (int r = 0; r < 4; ++r)
                sf[widx][g * 4 + r][jt * 16 + row] = acc[jt][r] + bc;
        }
        __builtin_amdgcn_s_waitcnt(0);
        #pragma unroll
        for (int it = 0; it < 8; ++it) {
            int rr = it * 2 + (lane >> 5);       // 0..15
            int c4 = lane & 31;                  // 16B chunk id
            int n = m0 + rr;
            float4 v = *(const float4*)&sf[widx][rr][c4 * 4];
            if (n < n_nodes)
                *(float4*)(m2 + (size_t)n * HD + c4 * 4) = v;
        }
    }
}

// ---------------- hierarchical scan ----------------

__global__ __launch_bounds__(1024) void scan_blocks(
    const int* __restrict__ deg, int* __restrict__ off,
    int* __restrict__ bsum, int n_nodes)
{
    __shared__ int wtot[16];
    const int t = threadIdx.x;
    const int lane = t & 63;
    const int wid = t >> 6;
    int idx = blockIdx.x * 1024 + t;
    int v = (idx < n_nodes) ? deg[idx] : 0;
    int incl = v;
    #pragma unroll
    for (int o = 1; o < 64; o <<= 1) {
        int y = __shfl_up(incl, o, 64);
        if (lane >= o) incl += y;
    }
    if (lane == 63) wtot[wid] = incl;
    __syncthreads();
    if (wid == 0) {
        int w = (lane < 16) ? wtot[lane] : 0;
        int wi = w;
        #pragma unroll
        for (int o = 1; o < 16; o <<= 1) {
            int y = __shfl_up(wi, o, 64);
            if (lane >= o) wi += y;
        }
        if (lane < 16) wtot[lane] = wi - w;
    }
    __syncthreads();
    int excl = wtot[wid] + incl - v;
    if (idx < n_nodes) off[idx] = excl;
    if (t == 1023) bsum[blockIdx.x] = wtot[15] + incl;
}

__global__ __launch_bounds__(64) void scan_partials(int* __restrict__ bsum, int nb)
{
    const int lane = threadIdx.x;
    int carry = 0;
    for (int base = 0; base < nb; base += 64) {
        int i = base + lane;
        int v = (i < nb) ? bsum[i] : 0;
        int incl = v;
        #pragma unroll
        for (int o = 1; o < 64; o <<= 1) {
            int y = __shfl_up(incl, o, 64);
            if (lane >= o) incl += y;
        }
        if (i < nb) bsum[i] = carry + incl - v;
        carry += __shfl(incl, 63, 64);
    }
}

__global__ __launch_bounds__(1024) void scan_apply(
    int* __restrict__ off, int* __restrict__ cur,
    const int* __restrict__ bsum, int n_nodes, int n_edges)
{
    int idx = blockIdx.x * 1024 + threadIdx.x;
    if (idx < n_nodes) {
        int v = off[idx] + bsum[blockIdx.x];
        off[idx] = v;
        cur[idx] = v;
    }
    if (idx == 0) off[n_nodes] = n_edges;
}

__global__ __launch_bounds__(256) void edge_fill(
    const int* __restrict__ src, const int* __restrict__ dst,
    int* __restrict__ cur, int* __restrict__ elist, int n_edges)
{
    int e = blockIdx.x * 256 + threadIdx.x;
    if (e < n_edges) {
        int d = dst[e];
        int pos = atomicAdd(&cur[d], 1);
        elist[pos] = src[e];
    }
}

// ---- gather + full epilogue: out[n] = sigmoid(sum_e m1b[src] + deg*m2[n]) + softplus(h[n]) ----

__global__ __launch_bounds__(256) void gather_ep(
    const short* __restrict__ m1b, const int* __restrict__ off,
    const int* __restrict__ elist, const float* __restrict__ m2,
    const float* __restrict__ h, float* __restrict__ out, int n_nodes)
{
    int g = (blockIdx.x * 256 + threadIdx.x) >> 4;   // node
    int lane = threadIdx.x & 15;
    if (g >= n_nodes) return;
    int beg = off[g], end = off[g + 1];
    const size_t lo = (size_t)(lane * 8);

    float a0[8], a1[8];
    #pragma unroll
    for (int q = 0; q < 8; ++q) { a0[q] = 0.f; a1[q] = 0.f; }

    int i = beg;
    for (; i + 4 <= end; i += 4) {
        int s0 = elist[i], s1 = elist[i + 1], s2 = elist[i + 2], s3 = elist[i + 3];
        uint4 v0 = *(const uint4*)(m1b + (size_t)s0 * HD + lo);
        uint4 v1 = *(const uint4*)(m1b + (size_t)s1 * HD + lo);
        uint4 v2 = *(const uint4*)(m1b + (size_t)s2 * HD + lo);
        uint4 v3 = *(const uint4*)(m1b + (size_t)s3 * HD + lo);
        accum8(a0, v0); accum8(a1, v1);
        accum8(a0, v2); accum8(a1, v3);
    }
    for (; i < end; ++i) {
        int s0 = elist[i];
        uint4 v0 = *(const uint4*)(m1b + (size_t)s0 * HD + lo);
        accum8(a0, v0);
    }

    const float dg = (float)(end - beg);
    const float4* pm = (const float4*)(m2 + (size_t)g * HD + lo);
    const float4* ph = (const float4*)(h + (size_t)g * HD + lo);
    float4 ma = pm[0], mb = pm[1], ha = ph[0], hb4 = ph[1];

    float mr[8] = { ma.x, ma.y, ma.z, ma.w, mb.x, mb.y, mb.z, mb.w };
    float hr[8] = { ha.x, ha.y, ha.z, ha.w, hb4.x, hb4.y, hb4.z, hb4.w };

    float o[8];
    #pragma unroll
    for (int q = 0; q < 8; ++q) {
        float agg = (a0[q] + a1[q]) + dg * mr[q];
        o[q] = fast_sigmoid(agg) + fast_softplus(hr[q]);
    }
    float4* po = (float4*)(out + (size_t)g * HD + lo);
    po[0] = (float4){o[0], o[1], o[2], o[3]};
    po[1] = (float4){o[4], o[5], o[6], o[7]};
}

// ================== fallback tiers ==================

__global__ __launch_bounds__(256) void wt_convert(
    const float* __restrict__ W, short* __restrict__ Wt)
{
    int idx = blockIdx.x * 256 + threadIdx.x;
    int j = idx >> 8;
    int k = idx & 255;
    Wt[idx] = f2bf(W[k * HD + j]);
}

__global__ __launch_bounds__(256) void mpnn_scatter(
    const float* __restrict__ h, const int* __restrict__ src,
    const int* __restrict__ dst, float* __restrict__ S,
    int* __restrict__ deg, int n_edges)
{
    int gid = blockIdx.x * 256 + threadIdx.x;
    int e = gid >> 5;
    if (e >= n_edges) return;
    int lane = gid & 31;
    int s = src[e], d = dst[e];
    float4 v = *(const float4*)(h + (size_t)s * HD + lane * 4);
    float* srow = S + (size_t)d * HD + lane * 4;
    atomicAdd(srow + 0, v.x);
    atomicAdd(srow + 1, v.y);
    atomicAdd(srow + 2, v.z);
    atomicAdd(srow + 3, v.w);
    if (lane == 0) atomicAdd(deg + d, 1);
}

__global__ __launch_bounds__(256) void mpnn_node_mfma(
    const float* __restrict__ h,
    const short* __restrict__ Wt,    // [128][256]
    const float* __restrict__ bias,
    const int* __restrict__ deg,
    float* __restrict__ S,
    int n_nodes)
{
    const int lane = threadIdx.x & 63;
    const int wv = threadIdx.x >> 6;
    const int m0 = blockIdx.x * 32 + (wv >> 1) * 16;
    const int c0 = (wv & 1) * 64;
    if (m0 >= n_nodes) return;
    const int row = lane & 15;
    const int g = lane >> 4;

    const int nBase = m0 + g * 4;
    float dgO[4], hv[4][4], bc[4];
    #pragma unroll
    for (int r = 0; r < 4; ++r) {
        int n = nBase + r;
        int nc = (n < n_nodes) ? n : (n_nodes - 1);
        dgO[r] = (float)deg[nc];
        #pragma unroll
        for (int jt = 0; jt < 4; ++jt)
            hv[jt][r] = h[(size_t)nc * HD + c0 + jt * 16 + row];
    }
    #pragma unroll
    for (int jt = 0; jt < 4; ++jt) bc[jt] = bias[c0 + jt * 16 + row];

    int mA = m0 + row;
    if (mA > n_nodes - 1) mA = n_nodes - 1;
    const float dgA = (float)deg[mA];

    bf16x8 a[8];
    #pragma unroll
    for (int kf = 0; kf < 4; ++kf) {
        const float4* p = (const float4*)(S + (size_t)mA * HD + kf * 32 + g * 8);
        float4 x = p[0], y = p[1];
        bf16x8 t = { f2bf(x.x), f2bf(x.y), f2bf(x.z), f2bf(x.w),
                     f2bf(y.x), f2bf(y.y), f2bf(y.z), f2bf(y.w) };
        a[kf] = t;
    }
    #pragma unroll
    for (int kf = 0; kf < 4; ++kf) {
        const float4* p = (const float4*)(h + (size_t)mA * HD + kf * 32 + g * 8);
        float4 x = p[0], y = p[1];
        bf16x8 t = { f2bf(dgA * x.x), f2bf(dgA * x.y), f2bf(dgA * x.z), f2bf(dgA * x.w),
                     f2bf(dgA * y.x), f2bf(dgA * y.y), f2bf(dgA * y.z), f2bf(dgA * y.w) };
        a[4 + kf] = t;
    }

    f32x4 acc[4];
    #pragma unroll
    for (int jt = 0; jt < 4; ++jt) acc[jt] = (f32x4){0.f, 0.f, 0.f, 0.f};

    #pragma unroll
    for (int jt = 0; jt < 4; ++jt) {
        const short* wj = Wt + (size_t)(c0 + jt * 16 + row) * 256 + g * 8;
        #pragma unroll
        for (int kf = 0; kf < 8; ++kf) {
            bf16x8 bf = *(const bf16x8*)(wj + kf * 32);
            acc[jt] = __builtin_amdgcn_mfma_f32_16x16x32_bf16(a[kf], bf, acc[jt], 0, 0, 0);
        }
    }

    #pragma unroll
    for (int jt = 0; jt < 4; ++jt) {
        const int col = c0 + jt * 16 + row;
        #pragma unroll
        for (int r = 0; r < 4; ++r) {
            int n = nBase + r;
            if (n < n_nodes) {
                float agg = acc[jt][r] + dgO[r] * bc[jt];
                S[(size_t)n * HD + col] = fast_sigmoid(agg) + fast_softplus(hv[jt][r]);
            }
        }
    }
}

__global__ __launch_bounds__(256) void mpnn_node_f32(
    const float* __restrict__ h, const float* __restrict__ W,
    const float* __restrict__ b, const int* __restrict__ deg,
    float* __restrict__ S, int n_nodes)
{
    const int j = threadIdx.x & (HD - 1);
    const int g = threadIdx.x >> 7;
    const int n0 = blockIdx.x * NPB + g * RPT;

    float accS[RPT], accH[RPT];
    #pragma unroll
    for (int r = 0; r < RPT; ++r) { accS[r] = 0.f; accH[r] = 0.f; }

    int rmax = n_nodes - n0;
    if (rmax > RPT) rmax = RPT;
    if (rmax < 0) rmax = 0;

    for (int k = 0; k < HD; k += 4) {
        float w0 = W[(k + 0) * HD + j], w1 = W[(k + 1) * HD + j];
        float w2 = W[(k + 2) * HD + j], w3 = W[(k + 3) * HD + j];
        #pragma unroll
        for (int r = 0; r < RPT; ++r) if (r < rmax) {
            float4 a = *(const float4*)(S + (size_t)(n0 + r) * HD + k);
            accS[r] = fmaf(a.x, w0, fmaf(a.y, w1, fmaf(a.z, w2, fmaf(a.w, w3, accS[r]))));
        }
    }
    for (int k = 0; k < HD; k += 4) {
        float w0 = W[(HD + k + 0) * HD + j], w1 = W[(HD + k + 1) * HD + j];
        float w2 = W[(HD + k + 2) * HD + j], w3 = W[(HD + k + 3) * HD + j];
        #pragma unroll
        for (int r = 0; r < RPT; ++r) if (r < rmax) {
            float4 a = *(const float4*)(h + (size_t)(n0 + r) * HD + k);
            accH[r] = fmaf(a.x, w0, fmaf(a.y, w1, fmaf(a.z, w2, fmaf(a.w, w3, accH[r]))));
        }
    }
    __syncthreads();
    #pragma unroll
    for (int r = 0; r < RPT; ++r) if (r < rmax) {
        int n = n0 + r;
        float dg = (float)deg[n];
        float agg = accS[r] + dg * (accH[r] + b[j]);
        float hvv = h[(size_t)n * HD + j];
        S[(size_t)n * HD + j] = fast_sigmoid(agg) + fast_softplus(hvv);
    }
}

extern "C" void kernel_launch(void* const* d_in, const int* in_sizes, int n_in,
                              void* d_out, int out_size, void* d_ws, size_t ws_size,
                              hipStream_t stream)
{
    const float* h   = (const float*)d_in[0];
    const int*   src = (const int*)d_in[1];
    const int*   dst = (const int*)d_in[2];
    const float* W   = (const float*)d_in[3];
    const float* b   = (const float*)d_in[4];
    float* S = (float*)d_out;

    const int n_nodes = in_sizes[0] / HD;
    const int n_edges = in_sizes[1];
    const int WT_INTS = 2 * HD * HD / 2;
    const int nb = (n_nodes + 1023) / 1024;

    // ---- 16B-aligned ws layout for the transformed-gather path ----
    char* p = (char*)d_ws;
    auto align16 = [](char* q) { return (char*)(((uintptr_t)q + 15) & ~(uintptr_t)15); };
    p = align16(p); int* deg = (int*)p;     p += (size_t)n_nodes * 4;
    p = align16(p); int* off = (int*)p;     p += ((size_t)n_nodes + 1) * 4;
    p = align16(p); int* cur = (int*)p;     p += (size_t)n_nodes * 4;
    p = align16(p); int* elist = (int*)p;   p += (size_t)n_edges * 4;
    p = align16(p); short* WtG = (short*)p; p += (size_t)256 * HD * 2;
    p = align16(p); int* bsum = (int*)p;    p += (size_t)nb * 4;
    p = align16(p); short* m1b = (short*)p; p += (size_t)n_nodes * HD * 2;
    p = align16(p); float* m2 = (float*)p;  p += (size_t)n_nodes * HD * 4;
    const size_t need_top = (size_t)(p - (char*)d_ws);

    const size_t need_mid = ((size_t)n_nodes + WT_INTS + 8) * sizeof(int);

    if (ws_size >= need_top) {
        hipMemsetAsync(deg, 0, (size_t)n_nodes * sizeof(int), stream);
        wtg_hist<<<1024, 256, 0, stream>>>(W, WtG, dst, deg, n_edges);

        const int pblocks = (n_nodes + 31) / 32;
        prep_gemm<<<pblocks, 256, 0, stream>>>(h, WtG, b, m1b, m2, n_nodes);

        scan_blocks<<<nb, 1024, 0, stream>>>(deg, off, bsum, n_nodes);
        scan_partials<<<1, 64, 0, stream>>>(bsum, nb);
        scan_apply<<<nb, 1024, 0, stream>>>(off, cur, bsum, n_nodes, n_edges);

        edge_fill<<<(n_edges + 255) / 256, 256, 0, stream>>>(src, dst, cur, elist, n_edges);

        const int gblocks = (int)(((long long)n_nodes * 16 + 255) / 256);
        gather_ep<<<gblocks, 256, 0, stream>>>(m1b, off, elist, m2, h, S, n_nodes);
    } else if (ws_size >= need_mid) {
        // atomic scatter + MFMA node kernel
        int* deg2  = (int*)d_ws;
        short* Wt2 = (short*)(deg2 + n_nodes);
        hipMemsetAsync(d_out, 0, (size_t)n_nodes * HD * sizeof(float), stream);
        hipMemsetAsync(deg2, 0, (size_t)n_nodes * sizeof(int), stream);
        wt_convert<<<(2 * HD * HD) / 256, 256, 0, stream>>>(W, Wt2);
        const int sblocks = (int)(((long long)n_edges * 32 + 255) / 256);
        mpnn_scatter<<<sblocks, 256, 0, stream>>>(h, src, dst, S, deg2, n_edges);
        const int mblocks = (n_nodes + 31) / 32;
        mpnn_node_mfma<<<mblocks, 256, 0, stream>>>(h, Wt2, b, deg2, S, n_nodes);
    } else {
        int* deg2 = (int*)d_ws;
        hipMemsetAsync(d_out, 0, (size_t)n_nodes * HD * sizeof(float), stream);
        hipMemsetAsync(deg2, 0, (size_t)n_nodes * sizeof(int), stream);
        const int sblocks = (int)(((long long)n_edges * 32 + 255) / 256);
        mpnn_scatter<<<sblocks, 256, 0, stream>>>(h, src, dst, S, deg2, n_edges);
        const int nblocks = (n_nodes + NPB - 1) / NPB;
        mpnn_node_f32<<<nblocks, 256, 0, stream>>>(h, W, b, deg2, S, n_nodes);
    }
}

// Round 11
// 141.949 us; speedup vs baseline: 1.1200x; 1.0807x over previous
//
#include <hip/hip_runtime.h>
#include <math.h>

#define HD 128
#define NPB 16
#define RPT 8

typedef __attribute__((ext_vector_type(8))) short bf16x8;
typedef __attribute__((ext_vector_type(4))) float f32x4;

__device__ inline short f2bf(float x) {   // RTNE f32->bf16
    union { float f; unsigned u; } v; v.f = x;
    unsigned r = v.u + 0x7fff + ((v.u >> 16) & 1);
    return (short)(r >> 16);
}
__device__ inline float bf2f(short x) {
    union { unsigned u; float f; } v;
    v.u = ((unsigned)(unsigned short)x) << 16;
    return v.f;
}

#define LOG2E 1.4426950408889634f
#define LN2   0.6931471805599453f

__device__ inline float fast_sigmoid(float x) {
    return __builtin_amdgcn_rcpf(1.0f + __builtin_amdgcn_exp2f(-LOG2E * x));
}
__device__ inline float fast_softplus(float x) {
    float t = __builtin_amdgcn_exp2f(-LOG2E * fabsf(x));
    return fmaxf(x, 0.0f) + LN2 * __builtin_amdgcn_logf(1.0f + t);
}

__device__ inline void accum8(float* a, const uint4 u) {  // += 8 bf16 packed in uint4
    a[0] += __uint_as_float(u.x << 16);
    a[1] += __uint_as_float(u.x & 0xffff0000u);
    a[2] += __uint_as_float(u.y << 16);
    a[3] += __uint_as_float(u.y & 0xffff0000u);
    a[4] += __uint_as_float(u.z << 16);
    a[5] += __uint_as_float(u.z & 0xffff0000u);
    a[6] += __uint_as_float(u.w << 16);
    a[7] += __uint_as_float(u.w & 0xffff0000u);
}

// ---- fast zero (replaces the pathologically slow hipMemsetAsync fill) ----
__global__ __launch_bounds__(256) void zero_i32(int* __restrict__ p, int n)
{
    int i = blockIdx.x * 256 + threadIdx.x;
    if (i < n) p[i] = 0;
}

// ---- WtG build + degree histogram ----
// WtG[j][k] = bf16(Wcat[k][j]), j in 0..255 (j<128: W1 col j; j>=128: W2 col j-128), k in 0..127

__global__ __launch_bounds__(256) void wtg_hist(
    const float* __restrict__ W, short* __restrict__ WtG,
    const int* __restrict__ dst, int* __restrict__ deg, int n_edges)
{
    const int tid = blockIdx.x * 256 + threadIdx.x;
    const int total = gridDim.x * 256;
    for (int i = tid; i < 256 * 128; i += total) {
        int j = i >> 7, k = i & 127;
        float w = (j < HD) ? W[k * HD + j] : W[(HD + k) * HD + (j - HD)];
        WtG[i] = f2bf(w);
    }
    for (int e = tid; e < n_edges; e += total)
        atomicAdd(&deg[dst[e]], 1);
}

// ---- dense prep GEMM: m1b = bf16(h@W1), m2 = h@W2 + b ----
// Block = 128 rows (8 tiles of 16), 4 waves: wave = (half, colhalf), 64 cols.
// B panel (16 bf16x8) lives in registers for the whole kernel; next tile's
// A-loads are issued under the current tile's MFMAs (1-deep pipeline).
// A/B both use k = kf*32 + g*8 + slot (consistent bijection -> exact).
// C/D: col = lane&15, row = (lane>>4)*4 + reg  [HW-verified m89/m91].

__global__ __launch_bounds__(256) void prep_gemm(
    const float* __restrict__ h,     // [N][128] f32
    const short* __restrict__ WtG,   // [256][128] bf16
    const float* __restrict__ bias,  // [128] f32
    short* __restrict__ m1b,         // [N][128] bf16 out
    float* __restrict__ m2,          // [N][128] f32 out (h@W2 + b)
    int n_nodes)
{
    __shared__ short sb[2][16][72];   // half=0 staging, padded (bank-rotate)
    __shared__ float sf[2][16][68];   // half=1 staging, padded

    const int lane = threadIdx.x & 63;
    const int wv = threadIdx.x >> 6;           // 0..3
    const int half = wv & 1;                   // 0: m1b, 1: m2
    const int ch = wv >> 1;                    // col half
    const int c0 = ch * 64;
    const int row = lane & 15;
    const int g = lane >> 4;
    const int mBlk = blockIdx.x * 128;

    // ---- B panel in registers (64 cols x K=128) ----
    bf16x8 B[4][4];
    #pragma unroll
    for (int jt = 0; jt < 4; ++jt) {
        const short* wj = WtG + (size_t)(half * HD + c0 + jt * 16 + row) * HD + g * 8;
        #pragma unroll
        for (int kf = 0; kf < 4; ++kf)
            B[jt][kf] = *(const bf16x8*)(wj + kf * 32);
    }
    float bc[4];
    #pragma unroll
    for (int jt = 0; jt < 4; ++jt) bc[jt] = bias[c0 + jt * 16 + row];

    // ---- prefetch A for tile 0 ----
    float4 af[8];
    {
        int mA = mBlk + row; if (mA > n_nodes - 1) mA = n_nodes - 1;
        #pragma unroll
        for (int kf = 0; kf < 4; ++kf) {
            af[2 * kf]     = *(const float4*)(h + (size_t)mA * HD + kf * 32 + g * 8);
            af[2 * kf + 1] = *(const float4*)(h + (size_t)mA * HD + kf * 32 + g * 8 + 4);
        }
    }

    for (int tt = 0; tt < 8; ++tt) {
        const int m0 = mBlk + tt * 16;

        // convert current A
        bf16x8 a[4];
        #pragma unroll
        for (int kf = 0; kf < 4; ++kf) {
            float4 x = af[2 * kf], y = af[2 * kf + 1];
            bf16x8 t = { f2bf(x.x), f2bf(x.y), f2bf(x.z), f2bf(x.w),
                         f2bf(y.x), f2bf(y.y), f2bf(y.z), f2bf(y.w) };
            a[kf] = t;
        }
        // issue next tile's A-loads (fly under the MFMAs below)
        if (tt < 7) {
            int mN = m0 + 16 + row; if (mN > n_nodes - 1) mN = n_nodes - 1;
            #pragma unroll
            for (int kf = 0; kf < 4; ++kf) {
                af[2 * kf]     = *(const float4*)(h + (size_t)mN * HD + kf * 32 + g * 8);
                af[2 * kf + 1] = *(const float4*)(h + (size_t)mN * HD + kf * 32 + g * 8 + 4);
            }
        }

        f32x4 acc[4];
        #pragma unroll
        for (int jt = 0; jt < 4; ++jt) acc[jt] = (f32x4){0.f, 0.f, 0.f, 0.f};
        #pragma unroll
        for (int jt = 0; jt < 4; ++jt)
            #pragma unroll
            for (int kf = 0; kf < 4; ++kf)
                acc[jt] = __builtin_amdgcn_mfma_f32_16x16x32_bf16(a[kf], B[jt][kf], acc[jt], 0, 0, 0);

        // stage C-tile in wave-private LDS, then coalesced global stores
        if (half == 0) {
            #pragma unroll
            for (int jt = 0; jt < 4; ++jt)
                #pragma unroll
                for (int r = 0; r < 4; ++r)
                    sb[ch][g * 4 + r][jt * 16 + row] = f2bf(acc[jt][r]);
            asm volatile("s_waitcnt lgkmcnt(0)" ::: "memory");
            #pragma unroll
            for (int ps = 0; ps < 2; ++ps) {
                int rr = ps * 8 + (lane >> 3);
                int c8 = lane & 7;
                int n = m0 + rr;
                bf16x8 v = *(const bf16x8*)&sb[ch][rr][c8 * 8];
                if (n < n_nodes)
                    *(bf16x8*)(m1b + (size_t)n * HD + c0 + c8 * 8) = v;
            }
        } else {
            #pragma unroll
            for (int jt = 0; jt < 4; ++jt)
                #pragma unroll
                for (int r = 0; r < 4; ++r)
                    sf[ch][g * 4 + r][jt * 16 + row] = acc[jt][r] + bc[jt];
            asm volatile("s_waitcnt lgkmcnt(0)" ::: "memory");
            #pragma unroll
            for (int ps = 0; ps < 4; ++ps) {
                int rr = ps * 4 + (lane >> 4);
                int c4 = lane & 15;
                int n = m0 + rr;
                float4 v = *(const float4*)&sf[ch][rr][c4 * 4];
                if (n < n_nodes)
                    *(float4*)(m2 + (size_t)n * HD + c0 + c4 * 4) = v;
            }
        }
    }
}

// ---------------- hierarchical scan ----------------

__global__ __launch_bounds__(1024) void scan_blocks(
    const int* __restrict__ deg, int* __restrict__ off,
    int* __restrict__ bsum, int n_nodes)
{
    __shared__ int wtot[16];
    const int t = threadIdx.x;
    const int lane = t & 63;
    const int wid = t >> 6;
    int idx = blockIdx.x * 1024 + t;
    int v = (idx < n_nodes) ? deg[idx] : 0;
    int incl = v;
    #pragma unroll
    for (int o = 1; o < 64; o <<= 1) {
        int y = __shfl_up(incl, o, 64);
        if (lane >= o) incl += y;
    }
    if (lane == 63) wtot[wid] = incl;
    __syncthreads();
    if (wid == 0) {
        int w = (lane < 16) ? wtot[lane] : 0;
        int wi = w;
        #pragma unroll
        for (int o = 1; o < 16; o <<= 1) {
            int y = __shfl_up(wi, o, 64);
            if (lane >= o) wi += y;
        }
        if (lane < 16) wtot[lane] = wi - w;
    }
    __syncthreads();
    int excl = wtot[wid] + incl - v;
    if (idx < n_nodes) off[idx] = excl;
    if (t == 1023) bsum[blockIdx.x] = wtot[15] + incl;
}

__global__ __launch_bounds__(64) void scan_partials(int* __restrict__ bsum, int nb)
{
    const int lane = threadIdx.x;
    int carry = 0;
    for (int base = 0; base < nb; base += 64) {
        int i = base + lane;
        int v = (i < nb) ? bsum[i] : 0;
        int incl = v;
        #pragma unroll
        for (int o = 1; o < 64; o <<= 1) {
            int y = __shfl_up(incl, o, 64);
            if (lane >= o) incl += y;
        }
        if (i < nb) bsum[i] = carry + incl - v;
        carry += __shfl(incl, 63, 64);
    }
}

__global__ __launch_bounds__(1024) void scan_apply(
    int* __restrict__ off, int* __restrict__ cur,
    const int* __restrict__ bsum, int n_nodes, int n_edges)
{
    int idx = blockIdx.x * 1024 + threadIdx.x;
    if (idx < n_nodes) {
        int v = off[idx] + bsum[blockIdx.x];
        off[idx] = v;
        cur[idx] = v;
    }
    if (idx == 0) off[n_nodes] = n_edges;
}

__global__ __launch_bounds__(256) void edge_fill(
    const int* __restrict__ src, const int* __restrict__ dst,
    int* __restrict__ cur, int* __restrict__ elist, int n_edges)
{
    int e = blockIdx.x * 256 + threadIdx.x;
    if (e < n_edges) {
        int d = dst[e];
        int pos = atomicAdd(&cur[d], 1);
        elist[pos] = src[e];
    }
}

// ---- gather + full epilogue: out[n] = sigmoid(sum_e m1b[src] + deg*m2[n]) + softplus(h[n]) ----

__global__ __launch_bounds__(256) void gather_ep(
    const short* __restrict__ m1b, const int* __restrict__ off,
    const int* __restrict__ elist, const float* __restrict__ m2,
    const float* __restrict__ h, float* __restrict__ out, int n_nodes)
{
    int g = (blockIdx.x * 256 + threadIdx.x) >> 4;   // node
    int lane = threadIdx.x & 15;
    if (g >= n_nodes) return;
    int beg = off[g], end = off[g + 1];
    const size_t lo = (size_t)(lane * 8);

    float a0[8], a1[8];
    #pragma unroll
    for (int q = 0; q < 8; ++q) { a0[q] = 0.f; a1[q] = 0.f; }

    int i = beg;
    for (; i + 4 <= end; i += 4) {
        int s0 = elist[i], s1 = elist[i + 1], s2 = elist[i + 2], s3 = elist[i + 3];
        uint4 v0 = *(const uint4*)(m1b + (size_t)s0 * HD + lo);
        uint4 v1 = *(const uint4*)(m1b + (size_t)s1 * HD + lo);
        uint4 v2 = *(const uint4*)(m1b + (size_t)s2 * HD + lo);
        uint4 v3 = *(const uint4*)(m1b + (size_t)s3 * HD + lo);
        accum8(a0, v0); accum8(a1, v1);
        accum8(a0, v2); accum8(a1, v3);
    }
    for (; i < end; ++i) {
        int s0 = elist[i];
        uint4 v0 = *(const uint4*)(m1b + (size_t)s0 * HD + lo);
        accum8(a0, v0);
    }

    const float dg = (float)(end - beg);
    const float4* pm = (const float4*)(m2 + (size_t)g * HD + lo);
    const float4* ph = (const float4*)(h + (size_t)g * HD + lo);
    float4 ma = pm[0], mb = pm[1], ha = ph[0], hb4 = ph[1];

    float mr[8] = { ma.x, ma.y, ma.z, ma.w, mb.x, mb.y, mb.z, mb.w };
    float hr[8] = { ha.x, ha.y, ha.z, ha.w, hb4.x, hb4.y, hb4.z, hb4.w };

    float o[8];
    #pragma unroll
    for (int q = 0; q < 8; ++q) {
        float agg = (a0[q] + a1[q]) + dg * mr[q];
        o[q] = fast_sigmoid(agg) + fast_softplus(hr[q]);
    }
    float4* po = (float4*)(out + (size_t)g * HD + lo);
    po[0] = (float4){o[0], o[1], o[2], o[3]};
    po[1] = (float4){o[4], o[5], o[6], o[7]};
}

// ================== fallback tiers ==================

__global__ __launch_bounds__(256) void wt_convert(
    const float* __restrict__ W, short* __restrict__ Wt)
{
    int idx = blockIdx.x * 256 + threadIdx.x;
    int j = idx >> 8;
    int k = idx & 255;
    Wt[idx] = f2bf(W[k * HD + j]);
}

__global__ __launch_bounds__(256) void mpnn_scatter(
    const float* __restrict__ h, const int* __restrict__ src,
    const int* __restrict__ dst, float* __restrict__ S,
    int* __restrict__ deg, int n_edges)
{
    int gid = blockIdx.x * 256 + threadIdx.x;
    int e = gid >> 5;
    if (e >= n_edges) return;
    int lane = gid & 31;
    int s = src[e], d = dst[e];
    float4 v = *(const float4*)(h + (size_t)s * HD + lane * 4);
    float* srow = S + (size_t)d * HD + lane * 4;
    atomicAdd(srow + 0, v.x);
    atomicAdd(srow + 1, v.y);
    atomicAdd(srow + 2, v.z);
    atomicAdd(srow + 3, v.w);
    if (lane == 0) atomicAdd(deg + d, 1);
}

__global__ __launch_bounds__(256) void mpnn_node_mfma(
    const float* __restrict__ h,
    const short* __restrict__ Wt,    // [128][256]
    const float* __restrict__ bias,
    const int* __restrict__ deg,
    float* __restrict__ S,
    int n_nodes)
{
    const int lane = threadIdx.x & 63;
    const int wv = threadIdx.x >> 6;
    const int m0 = blockIdx.x * 32 + (wv >> 1) * 16;
    const int c0 = (wv & 1) * 64;
    if (m0 >= n_nodes) return;
    const int row = lane & 15;
    const int g = lane >> 4;

    const int nBase = m0 + g * 4;
    float dgO[4], hv[4][4], bc[4];
    #pragma unroll
    for (int r = 0; r < 4; ++r) {
        int n = nBase + r;
        int nc = (n < n_nodes) ? n : (n_nodes - 1);
        dgO[r] = (float)deg[nc];
        #pragma unroll
        for (int jt = 0; jt < 4; ++jt)
            hv[jt][r] = h[(size_t)nc * HD + c0 + jt * 16 + row];
    }
    #pragma unroll
    for (int jt = 0; jt < 4; ++jt) bc[jt] = bias[c0 + jt * 16 + row];

    int mA = m0 + row;
    if (mA > n_nodes - 1) mA = n_nodes - 1;
    const float dgA = (float)deg[mA];

    bf16x8 a[8];
    #pragma unroll
    for (int kf = 0; kf < 4; ++kf) {
        const float4* p = (const float4*)(S + (size_t)mA * HD + kf * 32 + g * 8);
        float4 x = p[0], y = p[1];
        bf16x8 t = { f2bf(x.x), f2bf(x.y), f2bf(x.z), f2bf(x.w),
                     f2bf(y.x), f2bf(y.y), f2bf(y.z), f2bf(y.w) };
        a[kf] = t;
    }
    #pragma unroll
    for (int kf = 0; kf < 4; ++kf) {
        const float4* p = (const float4*)(h + (size_t)mA * HD + kf * 32 + g * 8);
        float4 x = p[0], y = p[1];
        bf16x8 t = { f2bf(dgA * x.x), f2bf(dgA * x.y), f2bf(dgA * x.z), f2bf(dgA * x.w),
                     f2bf(dgA * y.x), f2bf(dgA * y.y), f2bf(dgA * y.z), f2bf(dgA * y.w) };
        a[4 + kf] = t;
    }

    f32x4 acc[4];
    #pragma unroll
    for (int jt = 0; jt < 4; ++jt) acc[jt] = (f32x4){0.f, 0.f, 0.f, 0.f};

    #pragma unroll
    for (int jt = 0; jt < 4; ++jt) {
        const short* wj = Wt + (size_t)(c0 + jt * 16 + row) * 256 + g * 8;
        #pragma unroll
        for (int kf = 0; kf < 8; ++kf) {
            bf16x8 bf = *(const bf16x8*)(wj + kf * 32);
            acc[jt] = __builtin_amdgcn_mfma_f32_16x16x32_bf16(a[kf], bf, acc[jt], 0, 0, 0);
        }
    }

    #pragma unroll
    for (int jt = 0; jt < 4; ++jt) {
        const int col = c0 + jt * 16 + row;
        #pragma unroll
        for (int r = 0; r < 4; ++r) {
            int n = nBase + r;
            if (n < n_nodes) {
                float agg = acc[jt][r] + dgO[r] * bc[jt];
                S[(size_t)n * HD + col] = fast_sigmoid(agg) + fast_softplus(hv[jt][r]);
            }
        }
    }
}

__global__ __launch_bounds__(256) void mpnn_node_f32(
    const float* __restrict__ h, const float* __restrict__ W,
    const float* __restrict__ b, const int* __restrict__ deg,
    float* __restrict__ S, int n_nodes)
{
    const int j = threadIdx.x & (HD - 1);
    const int g = threadIdx.x >> 7;
    const int n0 = blockIdx.x * NPB + g * RPT;

    float accS[RPT], accH[RPT];
    #pragma unroll
    for (int r = 0; r < RPT; ++r) { accS[r] = 0.f; accH[r] = 0.f; }

    int rmax = n_nodes - n0;
    if (rmax > RPT) rmax = RPT;
    if (rmax < 0) rmax = 0;

    for (int k = 0; k < HD; k += 4) {
        float w0 = W[(k + 0) * HD + j], w1 = W[(k + 1) * HD + j];
        float w2 = W[(k + 2) * HD + j], w3 = W[(k + 3) * HD + j];
        #pragma unroll
        for (int r = 0; r < RPT; ++r) if (r < rmax) {
            float4 a = *(const float4*)(S + (size_t)(n0 + r) * HD + k);
            accS[r] = fmaf(a.x, w0, fmaf(a.y, w1, fmaf(a.z, w2, fmaf(a.w, w3, accS[r]))));
        }
    }
    for (int k = 0; k < HD; k += 4) {
        float w0 = W[(HD + k + 0) * HD + j], w1 = W[(HD + k + 1) * HD + j];
        float w2 = W[(HD + k + 2) * HD + j], w3 = W[(HD + k + 3) * HD + j];
        #pragma unroll
        for (int r = 0; r < RPT; ++r) if (r < rmax) {
            float4 a = *(const float4*)(h + (size_t)(n0 + r) * HD + k);
            accH[r] = fmaf(a.x, w0, fmaf(a.y, w1, fmaf(a.z, w2, fmaf(a.w, w3, accH[r]))));
        }
    }
    __syncthreads();
    #pragma unroll
    for (int r = 0; r < RPT; ++r) if (r < rmax) {
        int n = n0 + r;
        float dg = (float)deg[n];
        float agg = accS[r] + dg * (accH[r] + b[j]);
        float hvv = h[(size_t)n * HD + j];
        S[(size_t)n * HD + j] = fast_sigmoid(agg) + fast_softplus(hvv);
    }
}

extern "C" void kernel_launch(void* const* d_in, const int* in_sizes, int n_in,
                              void* d_out, int out_size, void* d_ws, size_t ws_size,
                              hipStream_t stream)
{
    const float* h   = (const float*)d_in[0];
    const int*   src = (const int*)d_in[1];
    const int*   dst = (const int*)d_in[2];
    const float* W   = (const float*)d_in[3];
    const float* b   = (const float*)d_in[4];
    float* S = (float*)d_out;

    const int n_nodes = in_sizes[0] / HD;
    const int n_edges = in_sizes[1];
    const int WT_INTS = 2 * HD * HD / 2;
    const int nb = (n_nodes + 1023) / 1024;

    // ---- 16B-aligned ws layout for the transformed-gather path ----
    char* p = (char*)d_ws;
    auto align16 = [](char* q) { return (char*)(((uintptr_t)q + 15) & ~(uintptr_t)15); };
    p = align16(p); int* deg = (int*)p;     p += (size_t)n_nodes * 4;
    p = align16(p); int* off = (int*)p;     p += ((size_t)n_nodes + 1) * 4;
    p = align16(p); int* cur = (int*)p;     p += (size_t)n_nodes * 4;
    p = align16(p); int* elist = (int*)p;   p += (size_t)n_edges * 4;
    p = align16(p); short* WtG = (short*)p; p += (size_t)256 * HD * 2;
    p = align16(p); int* bsum = (int*)p;    p += (size_t)nb * 4;
    p = align16(p); short* m1b = (short*)p; p += (size_t)n_nodes * HD * 2;
    p = align16(p); float* m2 = (float*)p;  p += (size_t)n_nodes * HD * 4;
    const size_t need_top = (size_t)(p - (char*)d_ws);

    const size_t need_mid = ((size_t)n_nodes + WT_INTS + 8) * sizeof(int);

    if (ws_size >= need_top) {
        zero_i32<<<(n_nodes + 255) / 256, 256, 0, stream>>>(deg, n_nodes);
        wtg_hist<<<1024, 256, 0, stream>>>(W, WtG, dst, deg, n_edges);

        const int pblocks = (n_nodes + 127) / 128;
        prep_gemm<<<pblocks, 256, 0, stream>>>(h, WtG, b, m1b, m2, n_nodes);

        scan_blocks<<<nb, 1024, 0, stream>>>(deg, off, bsum, n_nodes);
        scan_partials<<<1, 64, 0, stream>>>(bsum, nb);
        scan_apply<<<nb, 1024, 0, stream>>>(off, cur, bsum, n_nodes, n_edges);

        edge_fill<<<(n_edges + 255) / 256, 256, 0, stream>>>(src, dst, cur, elist, n_edges);

        const int gblocks = (int)(((long long)n_nodes * 16 + 255) / 256);
        gather_ep<<<gblocks, 256, 0, stream>>>(m1b, off, elist, m2, h, S, n_nodes);
    } else if (ws_size >= need_mid) {
        // atomic scatter + MFMA node kernel
        int* deg2  = (int*)d_ws;
        short* Wt2 = (short*)(deg2 + n_nodes);
        hipMemsetAsync(d_out, 0, (size_t)n_nodes * HD * sizeof(float), stream);
        zero_i32<<<(n_nodes + 255) / 256, 256, 0, stream>>>(deg2, n_nodes);
        wt_convert<<<(2 * HD * HD) / 256, 256, 0, stream>>>(W, Wt2);
        const int sblocks = (int)(((long long)n_edges * 32 + 255) / 256);
        mpnn_scatter<<<sblocks, 256, 0, stream>>>(h, src, dst, S, deg2, n_edges);
        const int mblocks = (n_nodes + 31) / 32;
        mpnn_node_mfma<<<mblocks, 256, 0, stream>>>(h, Wt2, b, deg2, S, n_nodes);
    } else {
        int* deg2 = (int*)d_ws;
        hipMemsetAsync(d_out, 0, (size_t)n_nodes * HD * sizeof(float), stream);
        zero_i32<<<(n_nodes + 255) / 256, 256, 0, stream>>>(deg2, n_nodes);
        const int sblocks = (int)(((long long)n_edges * 32 + 255) / 256);
        mpnn_scatter<<<sblocks, 256, 0, stream>>>(h, src, dst, S, deg2, n_edges);
        const int nblocks = (n_nodes + NPB - 1) / NPB;
        mpnn_node_f32<<<nblocks, 256, 0, stream>>>(h, W, b, deg2, S, n_nodes);
    }
}